// Round 1
// baseline (69.716 us; speedup 1.0000x reference)
//
#include <hip/hip_runtime.h>

#define NUM_IND   1000
#define EMBED_DIM 32

// Kernel 1: collapse the whole per-industry pipeline into a 1000x32 table.
// table[t] = relu(vars[t] @ W1 + b1) @ W2 + b2 + 0.1*emb[t]
__global__ void build_table_kernel(const float* __restrict__ vars,  // [1000,8]
                                   const float* __restrict__ W1,    // [8,16]
                                   const float* __restrict__ b1,    // [16]
                                   const float* __restrict__ W2,    // [16,32]
                                   const float* __restrict__ b2,    // [32]
                                   const float* __restrict__ emb,   // [1000,32]
                                   float* __restrict__ table)       // [1000,32]
{
    int t = blockIdx.x * blockDim.x + threadIdx.x;
    if (t >= NUM_IND) return;

    float v[8];
#pragma unroll
    for (int k = 0; k < 8; ++k) v[k] = vars[t * 8 + k];

    float h[16];
#pragma unroll
    for (int j = 0; j < 16; ++j) {
        float acc = b1[j];
#pragma unroll
        for (int k = 0; k < 8; ++k) acc = fmaf(v[k], W1[k * 16 + j], acc);
        h[j] = fmaxf(acc, 0.0f);
    }

#pragma unroll
    for (int j = 0; j < 32; ++j) {
        float acc = b2[j];
#pragma unroll
        for (int k = 0; k < 16; ++k) acc = fmaf(h[k], W2[k * 32 + j], acc);
        table[t * 32 + j] = acc + 0.1f * emb[t * 32 + j];
    }
}

// Kernel 2: pure gather. Thread-per-float4: gid>>3 = example, gid&7 = chunk.
// A wave's 64 lanes write one contiguous 1 KB segment (coalesced); 8 lanes
// share one idx (cache broadcast); table (128 KB) is L1/L2-resident.
__global__ void gather_kernel(const int* __restrict__ idx,
                              const float4* __restrict__ table4,  // [1000*8]
                              float4* __restrict__ out4,          // [B*8]
                              int total4)                          // B*8
{
    int stride = gridDim.x * blockDim.x;
    for (int g = blockIdx.x * blockDim.x + threadIdx.x; g < total4; g += stride) {
        int ex = g >> 3;
        int c  = g & 7;
        int id = idx[ex];
        out4[g] = table4[id * 8 + c];
    }
}

extern "C" void kernel_launch(void* const* d_in, const int* in_sizes, int n_in,
                              void* d_out, int out_size, void* d_ws, size_t ws_size,
                              hipStream_t stream) {
    const int*   idx  = (const int*)  d_in[0];  // [B] int32
    const float* vars = (const float*)d_in[1];  // [1000,8]
    const float* W1   = (const float*)d_in[2];  // [8,16]
    const float* b1   = (const float*)d_in[3];  // [16]
    const float* W2   = (const float*)d_in[4];  // [16,32]
    const float* b2   = (const float*)d_in[5];  // [32]
    const float* emb  = (const float*)d_in[6];  // [1000,32]

    float* table = (float*)d_ws;                // 1000*32*4 = 128 KB
    float* out   = (float*)d_out;               // [B,32]

    const int B = in_sizes[0];

    // Build the 1000x32 table (4 blocks x 256 = 1024 threads >= 1000).
    build_table_kernel<<<4, 256, 0, stream>>>(vars, W1, b1, W2, b2, emb, table);

    // Gather: B*8 float4 elements, grid-stride over 2048 blocks.
    int total4 = B * 8;
    int blocks = 2048;
    gather_kernel<<<blocks, 256, 0, stream>>>(idx, (const float4*)table,
                                              (float4*)out, total4);
}